// Round 6
// baseline (2046.424 us; speedup 1.0000x reference)
//
#include <hip/hip_runtime.h>
#include <math.h>

typedef __bf16 bf16;
typedef __attribute__((ext_vector_type(4))) __bf16 bf16x4;
typedef __attribute__((ext_vector_type(8))) __bf16 bf16x8;
typedef __attribute__((ext_vector_type(4))) float f32x4;

#define T_STEPS 128
#define B_SZ    256
#define V_SZ    256
#define N_SZ    1024
#define NROWS   (T_STEPS * B_SZ)   // 32768
#define LDSS    72                 // padded LDS stride (bf16 elems)

#define GRP     8                  // row groups (ideally one per XCD via bid&7)
#define GR      (B_SZ / GRP)       // 32 batch rows per group
#define SLOTS   32                 // blocks per group (one per CU of the XCD)

__device__ __forceinline__ float fast_tanh(float x) {
    float e = __expf(2.0f * x);
    return 1.0f - 2.0f / (e + 1.0f);   // exact at +-inf, no NaN
}

// ---------------- fp32 -> bf16 contiguous convert ----------------
__global__ void k_convert(const float* __restrict__ src, bf16* __restrict__ dst, int n) {
    int i = (blockIdx.x * blockDim.x + threadIdx.x) * 4;
    if (i < n) {
        float4 v = *(const float4*)(src + i);
        bf16x4 o;
        o.x = (bf16)v.x; o.y = (bf16)v.y; o.z = (bf16)v.z; o.w = (bf16)v.w;
        *(bf16x4*)(dst + i) = o;
    }
}

// ---------------- fp32 (R x C) -> bf16 transpose (C x R) ----------------
__global__ void k_transpose_cvt(const float* __restrict__ src, bf16* __restrict__ dst,
                                int R, int C) {
    __shared__ float tile[32][33];
    int c0 = blockIdx.x * 32;
    int r0 = blockIdx.y * 32;
    int tx = threadIdx.x & 31;
    int ty = threadIdx.x >> 5;   // 0..7
#pragma unroll
    for (int i = 0; i < 32; i += 8)
        tile[ty + i][tx] = src[(size_t)(r0 + ty + i) * C + c0 + tx];
    __syncthreads();
#pragma unroll
    for (int i = 0; i < 32; i += 8)
        dst[(size_t)(c0 + ty + i) * R + r0 + tx] = (bf16)tile[tx][ty + i];
}

// ---------------- Xproj: XH[i][n] = bf16( X[i]@Wx[:,n] + bias[n] ) ----------------
// Rows with i < B_SZ are t=0: fold in h0 = tanh(Xproj0) since h_init = 0.
__global__ __launch_bounds__(256) void k_xproj(
    const bf16* __restrict__ X, const bf16* __restrict__ Wxt,
    const float* __restrict__ bias, bf16* __restrict__ XH)
{
    __shared__ __align__(16) bf16 As[64 * LDSS];
    __shared__ __align__(16) bf16 Bs[64 * LDSS];
    const int tid  = threadIdx.x;
    const int lane = tid & 63;
    const int w    = tid >> 6;
    const int wm   = (w >> 1) * 32;
    const int wn   = (w & 1) * 32;
    const int quad = lane >> 4;
    const int l15  = lane & 15;
    const int m0 = blockIdx.x * 64;
    const int n0 = blockIdx.y * 64;

    const bf16* Ag = X + (size_t)m0 * V_SZ;
    const bf16* Bg = Wxt + (size_t)n0 * V_SZ;

    f32x4 z = {0.f, 0.f, 0.f, 0.f};
    f32x4 acc00 = z, acc01 = z, acc10 = z, acc11 = z;

    for (int k0 = 0; k0 < V_SZ; k0 += 64) {
        {
            int c = tid, row = c >> 3, col = (c & 7) * 8;
            *(bf16x8*)&As[row * LDSS + col] = *(const bf16x8*)&Ag[(size_t)row * V_SZ + k0 + col];
            *(bf16x8*)&Bs[row * LDSS + col] = *(const bf16x8*)&Bg[(size_t)row * V_SZ + k0 + col];
            c = tid + 256; row = c >> 3; col = (c & 7) * 8;
            *(bf16x8*)&As[row * LDSS + col] = *(const bf16x8*)&Ag[(size_t)row * V_SZ + k0 + col];
            *(bf16x8*)&Bs[row * LDSS + col] = *(const bf16x8*)&Bg[(size_t)row * V_SZ + k0 + col];
        }
        __syncthreads();
#pragma unroll
        for (int kc = 0; kc < 64; kc += 32) {
            bf16x8 a0 = *(const bf16x8*)&As[(wm + l15) * LDSS + kc + quad * 8];
            bf16x8 a1 = *(const bf16x8*)&As[(wm + 16 + l15) * LDSS + kc + quad * 8];
            bf16x8 b0 = *(const bf16x8*)&Bs[(wn + l15) * LDSS + kc + quad * 8];
            bf16x8 b1 = *(const bf16x8*)&Bs[(wn + 16 + l15) * LDSS + kc + quad * 8];
            acc00 = __builtin_amdgcn_mfma_f32_16x16x32_bf16(a0, b0, acc00, 0, 0, 0);
            acc01 = __builtin_amdgcn_mfma_f32_16x16x32_bf16(a0, b1, acc01, 0, 0, 0);
            acc10 = __builtin_amdgcn_mfma_f32_16x16x32_bf16(a1, b0, acc10, 0, 0, 0);
            acc11 = __builtin_amdgcn_mfma_f32_16x16x32_bf16(a1, b1, acc11, 0, 0, 0);
        }
        __syncthreads();
    }
    bf16* Out = XH + (size_t)m0 * N_SZ + n0;
    const f32x4 accs[2][2] = {{acc00, acc01}, {acc10, acc11}};
#pragma unroll
    for (int mi = 0; mi < 2; ++mi)
#pragma unroll
        for (int r = 0; r < 4; ++r) {
            int row = wm + mi * 16 + quad * 4 + r;
            bool is_t0 = (m0 + row) < B_SZ;   // t=0 rows: apply tanh (h_prev = 0)
#pragma unroll
            for (int ni = 0; ni < 2; ++ni) {
                int col = wn + ni * 16 + l15;
                float pre = accs[mi][ni][r] + bias[n0 + col];
                if (is_t0) pre = fast_tanh(pre);
                Out[(size_t)row * N_SZ + col] = (bf16)pre;
            }
        }
}

// ---------------- persistent recurrence ----------------
// 256 blocks x 256 threads. group g = bid&7 owns batch rows [g*32,+32) for ALL t
// (groups are fully independent). slot s = bid>>3 owns output cols [s*32,+32).
// Wave w (of 4): 16x16 tile (mi=w>>1, ni=w&1), Wh^T slab in 128 VGPRs for all steps.
// Publishing: relaxed agent-scope atomics only (write-through to L3; no
// acquire-invalidate anywhere -> Wht stays L2-hot for the whole kernel).
__global__ __launch_bounds__(256, 1) void k_rnn(
    const bf16* __restrict__ Wht,   // 1024 x 1024 = Wh^T
    bf16* __restrict__ XH,
    int* __restrict__ cnt)          // [GRP * T_STEPS], zeroed
{
    const int tid  = threadIdx.x;
    const int lane = tid & 63;
    const int w    = tid >> 6;        // 0..3
    const int quad = lane >> 4;
    const int l15  = lane & 15;
    const int g    = blockIdx.x & 7;
    const int s    = blockIdx.x >> 3; // 0..31
    const int mi   = w >> 1;
    const int ni   = w & 1;
    const int mrow = g * GR + mi * 16;
    const int ncol = s * 32 + ni * 16;

    // ---- Wh^T slab into registers: 16 n-rows x K=1024 ----
    bf16x8 breg[32];
    const bf16* Bp = Wht + (size_t)(ncol + l15) * N_SZ + quad * 8;
#pragma unroll
    for (int kc = 0; kc < 32; ++kc)
        breg[kc] = *(const bf16x8*)&Bp[(size_t)kc * 32];

    unsigned short* XHu = (unsigned short*)XH;

    for (int t = 1; t < T_STEPS; ++t) {
        // prefetch Xproj terms via agent atomics (no L1/L2 allocation of lines
        // this step will overwrite -> no stale copies can exist anywhere)
        size_t obase = ((size_t)t * B_SZ + mrow + quad * 4) * N_SZ + ncol + l15;
        float xv[4];
#pragma unroll
        for (int r = 0; r < 4; ++r) {
            unsigned short u = __hip_atomic_load(&XHu[obase + (size_t)r * N_SZ],
                                                 __ATOMIC_RELAXED, __HIP_MEMORY_SCOPE_AGENT);
            xv[r] = (float)__builtin_bit_cast(bf16, u);
        }

        if (t > 1) {
            if (tid == 0) {
                while (__hip_atomic_load(&cnt[g * T_STEPS + t - 1],
                                         __ATOMIC_RELAXED, __HIP_MEMORY_SCOPE_AGENT) < SLOTS)
                    __builtin_amdgcn_s_sleep(1);
            }
            __syncthreads();
            __builtin_amdgcn_fence(__ATOMIC_ACQUIRE, "workgroup");  // waitcnt only, no cache inv
        }

        // A: 16 rows of H_{t-1} (fresh addresses -> L2 pulls fresh from L3)
        const bf16* Ap = XH + ((size_t)(t - 1) * B_SZ + mrow + l15) * N_SZ + quad * 8;
        f32x4 z = {0.f, 0.f, 0.f, 0.f};
        f32x4 acc0 = z, acc1 = z;
#pragma unroll
        for (int kc = 0; kc < 32; kc += 2) {
            bf16x8 a0 = *(const bf16x8*)&Ap[(size_t)kc * 32];
            bf16x8 a1 = *(const bf16x8*)&Ap[(size_t)(kc + 1) * 32];
            acc0 = __builtin_amdgcn_mfma_f32_16x16x32_bf16(a0, breg[kc], acc0, 0, 0, 0);
            acc1 = __builtin_amdgcn_mfma_f32_16x16x32_bf16(a1, breg[kc + 1], acc1, 0, 0, 0);
        }

        // publish H_t: relaxed agent atomic stores (write-through to L3)
#pragma unroll
        for (int r = 0; r < 4; ++r) {
            float v = fast_tanh(acc0[r] + acc1[r] + xv[r]);
            unsigned short u = __builtin_bit_cast(unsigned short, (bf16)v);
            __hip_atomic_store(&XHu[obase + (size_t)r * N_SZ], u,
                               __ATOMIC_RELAXED, __HIP_MEMORY_SCOPE_AGENT);
        }
        __builtin_amdgcn_fence(__ATOMIC_RELEASE, "agent");  // waitcnt (+wbl2: no dirty lines)
        __syncthreads();
        if (tid == 0)
            __hip_atomic_fetch_add(&cnt[g * T_STEPS + t], 1,
                                   __ATOMIC_RELAXED, __HIP_MEMORY_SCOPE_AGENT);
    }
}

// ---------------- fused logits + log-softmax + loss ----------------
// 256 blocks x 512 threads (8 waves), 128 rows/block; wave w owns rows w*16..+16.
__global__ __launch_bounds__(512, 4) void k_loss(
    const bf16* __restrict__ XH,
    const bf16* __restrict__ Wot,    // 256 x 1024 = Wout^T
    const float* __restrict__ ob,
    const float* __restrict__ labels,
    float* __restrict__ out)
{
    __shared__ __align__(16) bf16 As[128 * LDSS];   // 18.4 KB
    __shared__ __align__(16) bf16 Bs[256 * LDSS];   // 36.9 KB
    const int tid  = threadIdx.x;
    const int lane = tid & 63;
    const int w    = tid >> 6;      // 0..7
    const int quad = lane >> 4;
    const int l15  = lane & 15;
    const int m0 = blockIdx.x * 128;

    f32x4 z = {0.f, 0.f, 0.f, 0.f};
    f32x4 acc[16];
#pragma unroll
    for (int i = 0; i < 16; ++i) acc[i] = z;

    const bf16* Ag = XH + (size_t)m0 * N_SZ;
    for (int k0 = 0; k0 < N_SZ; k0 += 64) {
#pragma unroll
        for (int c = tid; c < 1024; c += 512) {
            int row = c >> 3, col = (c & 7) * 8;
            *(bf16x8*)&As[row * LDSS + col] = *(const bf16x8*)&Ag[(size_t)row * N_SZ + k0 + col];
        }
#pragma unroll
        for (int c = tid; c < 2048; c += 512) {
            int row = c >> 3, col = (c & 7) * 8;
            *(bf16x8*)&Bs[row * LDSS + col] = *(const bf16x8*)&Wot[(size_t)row * N_SZ + k0 + col];
        }
        __syncthreads();
#pragma unroll
        for (int kc = 0; kc < 64; kc += 32) {
            bf16x8 a = *(const bf16x8*)&As[(w * 16 + l15) * LDSS + kc + quad * 8];
#pragma unroll
            for (int nt = 0; nt < 16; ++nt) {
                bf16x8 b = *(const bf16x8*)&Bs[(nt * 16 + l15) * LDSS + kc + quad * 8];
                acc[nt] = __builtin_amdgcn_mfma_f32_16x16x32_bf16(a, b, acc[nt], 0, 0, 0);
            }
        }
        __syncthreads();
    }

    float obv[16];
#pragma unroll
    for (int nt = 0; nt < 16; ++nt) obv[nt] = ob[nt * 16 + l15];

    float total = 0.f;
#pragma unroll
    for (int r = 0; r < 4; ++r) {
        int row = m0 + w * 16 + quad * 4 + r;
        float vals[16];
        float lmax = -3.0e38f;
#pragma unroll
        for (int nt = 0; nt < 16; ++nt) {
            vals[nt] = acc[nt][r] + obv[nt];
            lmax = fmaxf(lmax, vals[nt]);
        }
#pragma unroll
        for (int s = 1; s < 16; s <<= 1)
            lmax = fmaxf(lmax, __shfl_xor(lmax, s, 64));
        float sume = 0.f, labv = 0.f, labs = 0.f;
        const float* lrow = labels + (size_t)row * V_SZ;
#pragma unroll
        for (int nt = 0; nt < 16; ++nt) {
            sume += __expf(vals[nt] - lmax);
            float lb = lrow[nt * 16 + l15];
            labv += lb * vals[nt];
            labs += lb;
        }
#pragma unroll
        for (int s = 1; s < 16; s <<= 1) {
            sume += __shfl_xor(sume, s, 64);
            labv += __shfl_xor(labv, s, 64);
            labs += __shfl_xor(labs, s, 64);
        }
        float lse = lmax + __logf(sume);
        total += labs * lse - labv;
    }
    if (l15 == 0)
        atomicAdd(out, total * (1.0f / (float)NROWS));
}

extern "C" void kernel_launch(void* const* d_in, const int* in_sizes, int n_in,
                              void* d_out, int out_size, void* d_ws, size_t ws_size,
                              hipStream_t stream)
{
    const float* inputs  = (const float*)d_in[0];
    const float* labels  = (const float*)d_in[1];
    const float* weights = (const float*)d_in[2];
    const float* bias    = (const float*)d_in[3];
    const float* out_w   = (const float*)d_in[4];
    const float* out_b   = (const float*)d_in[5];
    float* out = (float*)d_out;

    char* ws = (char*)d_ws;
    bf16* XH  = (bf16*)ws;  ws += (size_t)NROWS * N_SZ * 2;   // 64 MB, Xproj then H in place
    bf16* Xb  = (bf16*)ws;  ws += (size_t)NROWS * V_SZ * 2;   // 16 MB
    bf16* Wxt = (bf16*)ws;  ws += (size_t)N_SZ * V_SZ * 2;    // 0.5 MB (Wx^T: 1024x256)
    bf16* Wht = (bf16*)ws;  ws += (size_t)N_SZ * N_SZ * 2;    // 2 MB   (Wh^T: 1024x1024)
    bf16* Wot = (bf16*)ws;  ws += (size_t)V_SZ * N_SZ * 2;    // 0.5 MB (Wo^T: 256x1024)
    int*  cnt = (int*)ws;   ws += (size_t)GRP * T_STEPS * 4;  // 4 KB sync counters

    hipMemsetAsync(out, 0, sizeof(float), stream);
    hipMemsetAsync(cnt, 0, (size_t)GRP * T_STEPS * 4, stream);

    k_convert<<<dim3(NROWS * V_SZ / 1024), 256, 0, stream>>>(inputs, Xb, NROWS * V_SZ);
    k_transpose_cvt<<<dim3(N_SZ / 32, V_SZ / 32), 256, 0, stream>>>(weights, Wxt, V_SZ, N_SZ);
    k_transpose_cvt<<<dim3(N_SZ / 32, N_SZ / 32), 256, 0, stream>>>(
        weights + (size_t)V_SZ * N_SZ, Wht, N_SZ, N_SZ);
    k_transpose_cvt<<<dim3(V_SZ / 32, N_SZ / 32), 256, 0, stream>>>(out_w, Wot, N_SZ, V_SZ);

    k_xproj<<<dim3(NROWS / 64, N_SZ / 64), 256, 0, stream>>>(Xb, Wxt, bias, XH);

    k_rnn<<<dim3(GRP * SLOTS), 256, 0, stream>>>(Wht, XH, cnt);

    k_loss<<<dim3(NROWS / 128), 512, 0, stream>>>(XH, Wot, out_b, labels, out);
}

// Round 7
// 1056.521 us; speedup vs baseline: 1.9369x; 1.9369x over previous
//
#include <hip/hip_runtime.h>
#include <math.h>

typedef __bf16 bf16;
typedef __attribute__((ext_vector_type(4))) __bf16 bf16x4;
typedef __attribute__((ext_vector_type(8))) __bf16 bf16x8;
typedef __attribute__((ext_vector_type(4))) float f32x4;

#define T_STEPS 128
#define B_SZ    256
#define V_SZ    256
#define N_SZ    1024
#define NROWS   (T_STEPS * B_SZ)   // 32768
#define LDSS    72                 // padded LDS stride (bf16 elems)
#define RSTR    68                 // k_step reduction stride (floats)

__device__ __forceinline__ float fast_tanh(float x) {
    float e = __expf(2.0f * x);
    return 1.0f - 2.0f / (e + 1.0f);   // exact at +-inf, no NaN
}

// ---------------- fp32 -> bf16 contiguous convert ----------------
__global__ void k_convert(const float* __restrict__ src, bf16* __restrict__ dst, int n) {
    int i = (blockIdx.x * blockDim.x + threadIdx.x) * 4;
    if (i < n) {
        float4 v = *(const float4*)(src + i);
        bf16x4 o;
        o.x = (bf16)v.x; o.y = (bf16)v.y; o.z = (bf16)v.z; o.w = (bf16)v.w;
        *(bf16x4*)(dst + i) = o;
    }
}

// ---------------- fp32 (R x C) -> bf16 transpose (C x R) ----------------
__global__ void k_transpose_cvt(const float* __restrict__ src, bf16* __restrict__ dst,
                                int R, int C) {
    __shared__ float tile[32][33];
    int c0 = blockIdx.x * 32;
    int r0 = blockIdx.y * 32;
    int tx = threadIdx.x & 31;
    int ty = threadIdx.x >> 5;   // 0..7
#pragma unroll
    for (int i = 0; i < 32; i += 8)
        tile[ty + i][tx] = src[(size_t)(r0 + ty + i) * C + c0 + tx];
    __syncthreads();
#pragma unroll
    for (int i = 0; i < 32; i += 8)
        dst[(size_t)(c0 + ty + i) * R + r0 + tx] = (bf16)tile[tx][ty + i];
}

// ---------------- Xproj: XH[i][n] = bf16( X[i]@Wx[:,n] + bias[n] ) ----------------
// Rows with i < B_SZ are t=0: fold in h0 = tanh(Xproj0) since h_init = 0.
__global__ __launch_bounds__(256) void k_xproj(
    const bf16* __restrict__ X, const bf16* __restrict__ Wxt,
    const float* __restrict__ bias, bf16* __restrict__ XH)
{
    __shared__ __align__(16) bf16 As[64 * LDSS];
    __shared__ __align__(16) bf16 Bs[64 * LDSS];
    const int tid  = threadIdx.x;
    const int lane = tid & 63;
    const int w    = tid >> 6;
    const int wm   = (w >> 1) * 32;
    const int wn   = (w & 1) * 32;
    const int quad = lane >> 4;
    const int l15  = lane & 15;
    const int m0 = blockIdx.x * 64;
    const int n0 = blockIdx.y * 64;

    const bf16* Ag = X + (size_t)m0 * V_SZ;
    const bf16* Bg = Wxt + (size_t)n0 * V_SZ;

    f32x4 z = {0.f, 0.f, 0.f, 0.f};
    f32x4 acc00 = z, acc01 = z, acc10 = z, acc11 = z;

    for (int k0 = 0; k0 < V_SZ; k0 += 64) {
        {
            int c = tid, row = c >> 3, col = (c & 7) * 8;
            *(bf16x8*)&As[row * LDSS + col] = *(const bf16x8*)&Ag[(size_t)row * V_SZ + k0 + col];
            *(bf16x8*)&Bs[row * LDSS + col] = *(const bf16x8*)&Bg[(size_t)row * V_SZ + k0 + col];
            c = tid + 256; row = c >> 3; col = (c & 7) * 8;
            *(bf16x8*)&As[row * LDSS + col] = *(const bf16x8*)&Ag[(size_t)row * V_SZ + k0 + col];
            *(bf16x8*)&Bs[row * LDSS + col] = *(const bf16x8*)&Bg[(size_t)row * V_SZ + k0 + col];
        }
        __syncthreads();
#pragma unroll
        for (int kc = 0; kc < 64; kc += 32) {
            bf16x8 a0 = *(const bf16x8*)&As[(wm + l15) * LDSS + kc + quad * 8];
            bf16x8 a1 = *(const bf16x8*)&As[(wm + 16 + l15) * LDSS + kc + quad * 8];
            bf16x8 b0 = *(const bf16x8*)&Bs[(wn + l15) * LDSS + kc + quad * 8];
            bf16x8 b1 = *(const bf16x8*)&Bs[(wn + 16 + l15) * LDSS + kc + quad * 8];
            acc00 = __builtin_amdgcn_mfma_f32_16x16x32_bf16(a0, b0, acc00, 0, 0, 0);
            acc01 = __builtin_amdgcn_mfma_f32_16x16x32_bf16(a0, b1, acc01, 0, 0, 0);
            acc10 = __builtin_amdgcn_mfma_f32_16x16x32_bf16(a1, b0, acc10, 0, 0, 0);
            acc11 = __builtin_amdgcn_mfma_f32_16x16x32_bf16(a1, b1, acc11, 0, 0, 0);
        }
        __syncthreads();
    }
    bf16* Out = XH + (size_t)m0 * N_SZ + n0;
    const f32x4 accs[2][2] = {{acc00, acc01}, {acc10, acc11}};
#pragma unroll
    for (int mi = 0; mi < 2; ++mi)
#pragma unroll
        for (int r = 0; r < 4; ++r) {
            int row = wm + mi * 16 + quad * 4 + r;
            bool is_t0 = (m0 + row) < B_SZ;   // t=0 rows: apply tanh (h_prev = 0)
#pragma unroll
            for (int ni = 0; ni < 2; ++ni) {
                int col = wn + ni * 16 + l15;
                float pre = accs[mi][ni][r] + bias[n0 + col];
                if (is_t0) pre = fast_tanh(pre);
                Out[(size_t)row * N_SZ + col] = (bf16)pre;
            }
        }
}

// ---------------- recurrent step: XH[t] = tanh(XH[t] + XH[t-1] @ Wh), t >= 1 --------
// Grid (16 col-groups, 16 row-groups) = 256 blocks x 512 threads (8 waves, 1/CU).
// Wave w: K-slice [w*128,+128) of the block's 16x64 tile. ALL fragments (4 A +
// 16 B + Xproj) hoisted to registers up-front -> max memory-level parallelism,
// one wait, 16 MFMAs. One barrier for the 8-way K-reduce; coalesced dword stores.
// bx = col-group so B-sharing blocks share an XCD (bid%8 = bx%8).
__global__ __launch_bounds__(512, 2) void k_step(
    const bf16* __restrict__ Wht,   // 1024 x 1024 = Wh^T
    bf16* __restrict__ XH, int t)
{
    __shared__ float red[8 * 16 * RSTR];   // 34.8 KB
    const int tid  = threadIdx.x;
    const int lane = tid & 63;
    const int w    = tid >> 6;        // 0..7
    const int quad = lane >> 4;
    const int l15  = lane & 15;
    const int n0 = blockIdx.x * 64;
    const int m0 = blockIdx.y * 16;
    const int k0 = w * 128;

    // epilogue coords (2 outputs per thread, adjacent cols)
    const int orow = tid >> 5;           // 0..15
    const int ocol = (tid & 31) * 2;     // 0..62

    // issue Xproj prefetch first (in flight behind everything)
    bf16* Op = XH + ((size_t)t * B_SZ + m0 + orow) * N_SZ + n0 + ocol;
    uint xw = *(const uint*)Op;

    // hoist ALL fragment loads
    const bf16* Ap = XH + ((size_t)(t - 1) * B_SZ + m0 + l15) * N_SZ + k0 + quad * 8;
    const bf16* Bp = Wht + (size_t)(n0 + l15) * N_SZ + k0 + quad * 8;
    bf16x8 a[4], b[4][4];
#pragma unroll
    for (int kc = 0; kc < 4; ++kc)
        a[kc] = *(const bf16x8*)&Ap[kc * 32];
#pragma unroll
    for (int nt = 0; nt < 4; ++nt)
#pragma unroll
        for (int kc = 0; kc < 4; ++kc)
            b[nt][kc] = *(const bf16x8*)&Bp[(size_t)(nt * 16) * N_SZ + kc * 32];

    f32x4 z = {0.f, 0.f, 0.f, 0.f};
    f32x4 acc[4] = {z, z, z, z};
#pragma unroll
    for (int kc = 0; kc < 4; ++kc)
#pragma unroll
        for (int nt = 0; nt < 4; ++nt)
            acc[nt] = __builtin_amdgcn_mfma_f32_16x16x32_bf16(a[kc], b[nt][kc], acc[nt], 0, 0, 0);

    // 8-way K-reduce via LDS
#pragma unroll
    for (int nt = 0; nt < 4; ++nt)
#pragma unroll
        for (int r = 0; r < 4; ++r)
            red[(w * 16 + quad * 4 + r) * RSTR + nt * 16 + l15] = acc[nt][r];
    __syncthreads();

    float s0 = 0.f, s1 = 0.f;
#pragma unroll
    for (int w2 = 0; w2 < 8; ++w2) {
        float2 v = *(const float2*)&red[(w2 * 16 + orow) * RSTR + ocol];
        s0 += v.x; s1 += v.y;
    }
    bf16 x0 = __builtin_bit_cast(bf16, (unsigned short)(xw & 0xffff));
    bf16 x1 = __builtin_bit_cast(bf16, (unsigned short)(xw >> 16));
    bf16 r0 = (bf16)fast_tanh(s0 + (float)x0);
    bf16 r1 = (bf16)fast_tanh(s1 + (float)x1);
    uint outw = (uint)__builtin_bit_cast(unsigned short, r0)
              | ((uint)__builtin_bit_cast(unsigned short, r1) << 16);
    *(uint*)Op = outw;
}

// ---------------- fused logits + log-softmax + loss ----------------
// 256 blocks x 512 threads (8 waves), 128 rows/block; wave w owns rows w*16..+16.
__global__ __launch_bounds__(512, 4) void k_loss(
    const bf16* __restrict__ XH,
    const bf16* __restrict__ Wot,    // 256 x 1024 = Wout^T
    const float* __restrict__ ob,
    const float* __restrict__ labels,
    float* __restrict__ out)
{
    __shared__ __align__(16) bf16 As[128 * LDSS];   // 18.4 KB
    __shared__ __align__(16) bf16 Bs[256 * LDSS];   // 36.9 KB
    const int tid  = threadIdx.x;
    const int lane = tid & 63;
    const int w    = tid >> 6;      // 0..7
    const int quad = lane >> 4;
    const int l15  = lane & 15;
    const int m0 = blockIdx.x * 128;

    f32x4 z = {0.f, 0.f, 0.f, 0.f};
    f32x4 acc[16];
#pragma unroll
    for (int i = 0; i < 16; ++i) acc[i] = z;

    const bf16* Ag = XH + (size_t)m0 * N_SZ;
    for (int k0 = 0; k0 < N_SZ; k0 += 64) {
#pragma unroll
        for (int c = tid; c < 1024; c += 512) {
            int row = c >> 3, col = (c & 7) * 8;
            *(bf16x8*)&As[row * LDSS + col] = *(const bf16x8*)&Ag[(size_t)row * N_SZ + k0 + col];
        }
#pragma unroll
        for (int c = tid; c < 2048; c += 512) {
            int row = c >> 3, col = (c & 7) * 8;
            *(bf16x8*)&Bs[row * LDSS + col] = *(const bf16x8*)&Wot[(size_t)row * N_SZ + k0 + col];
        }
        __syncthreads();
#pragma unroll
        for (int kc = 0; kc < 64; kc += 32) {
            bf16x8 a = *(const bf16x8*)&As[(w * 16 + l15) * LDSS + kc + quad * 8];
#pragma unroll
            for (int nt = 0; nt < 16; ++nt) {
                bf16x8 b = *(const bf16x8*)&Bs[(nt * 16 + l15) * LDSS + kc + quad * 8];
                acc[nt] = __builtin_amdgcn_mfma_f32_16x16x32_bf16(a, b, acc[nt], 0, 0, 0);
            }
        }
        __syncthreads();
    }

    float obv[16];
#pragma unroll
    for (int nt = 0; nt < 16; ++nt) obv[nt] = ob[nt * 16 + l15];

    float total = 0.f;
#pragma unroll
    for (int r = 0; r < 4; ++r) {
        int row = m0 + w * 16 + quad * 4 + r;
        float vals[16];
        float lmax = -3.0e38f;
#pragma unroll
        for (int nt = 0; nt < 16; ++nt) {
            vals[nt] = acc[nt][r] + obv[nt];
            lmax = fmaxf(lmax, vals[nt]);
        }
#pragma unroll
        for (int s = 1; s < 16; s <<= 1)
            lmax = fmaxf(lmax, __shfl_xor(lmax, s, 64));
        float sume = 0.f, labv = 0.f, labs = 0.f;
        const float* lrow = labels + (size_t)row * V_SZ;
#pragma unroll
        for (int nt = 0; nt < 16; ++nt) {
            sume += __expf(vals[nt] - lmax);
            float lb = lrow[nt * 16 + l15];
            labv += lb * vals[nt];
            labs += lb;
        }
#pragma unroll
        for (int s = 1; s < 16; s <<= 1) {
            sume += __shfl_xor(sume, s, 64);
            labv += __shfl_xor(labv, s, 64);
            labs += __shfl_xor(labs, s, 64);
        }
        float lse = lmax + __logf(sume);
        total += labs * lse - labv;
    }
    if (l15 == 0)
        atomicAdd(out, total * (1.0f / (float)NROWS));
}

extern "C" void kernel_launch(void* const* d_in, const int* in_sizes, int n_in,
                              void* d_out, int out_size, void* d_ws, size_t ws_size,
                              hipStream_t stream)
{
    const float* inputs  = (const float*)d_in[0];
    const float* labels  = (const float*)d_in[1];
    const float* weights = (const float*)d_in[2];
    const float* bias    = (const float*)d_in[3];
    const float* out_w   = (const float*)d_in[4];
    const float* out_b   = (const float*)d_in[5];
    float* out = (float*)d_out;

    char* ws = (char*)d_ws;
    bf16* XH  = (bf16*)ws;  ws += (size_t)NROWS * N_SZ * 2;   // 64 MB, Xproj then H in place
    bf16* Xb  = (bf16*)ws;  ws += (size_t)NROWS * V_SZ * 2;   // 16 MB
    bf16* Wxt = (bf16*)ws;  ws += (size_t)N_SZ * V_SZ * 2;    // 0.5 MB (Wx^T: 1024x256)
    bf16* Wht = (bf16*)ws;  ws += (size_t)N_SZ * N_SZ * 2;    // 2 MB   (Wh^T: 1024x1024)
    bf16* Wot = (bf16*)ws;  ws += (size_t)V_SZ * N_SZ * 2;    // 0.5 MB (Wo^T: 256x1024)

    hipMemsetAsync(out, 0, sizeof(float), stream);

    k_convert<<<dim3(NROWS * V_SZ / 1024), 256, 0, stream>>>(inputs, Xb, NROWS * V_SZ);
    k_transpose_cvt<<<dim3(N_SZ / 32, V_SZ / 32), 256, 0, stream>>>(weights, Wxt, V_SZ, N_SZ);
    k_transpose_cvt<<<dim3(N_SZ / 32, N_SZ / 32), 256, 0, stream>>>(
        weights + (size_t)V_SZ * N_SZ, Wht, N_SZ, N_SZ);
    k_transpose_cvt<<<dim3(V_SZ / 32, N_SZ / 32), 256, 0, stream>>>(out_w, Wot, N_SZ, V_SZ);

    k_xproj<<<dim3(NROWS / 64, N_SZ / 64), 256, 0, stream>>>(Xb, Wxt, bias, XH);

    for (int t = 1; t < T_STEPS; ++t)
        k_step<<<dim3(N_SZ / 64, B_SZ / 16), 512, 0, stream>>>(Wht, XH, t);

    k_loss<<<dim3(NROWS / 128), 512, 0, stream>>>(XH, Wot, out_b, labels, out);
}

// Round 8
// 561.061 us; speedup vs baseline: 3.6474x; 1.8831x over previous
//
#include <hip/hip_runtime.h>
#include <math.h>

typedef __bf16 bf16;
typedef __attribute__((ext_vector_type(4))) __bf16 bf16x4;
typedef __attribute__((ext_vector_type(8))) __bf16 bf16x8;
typedef __attribute__((ext_vector_type(4))) float f32x4;

#define T_STEPS 128
#define B_SZ    256
#define V_SZ    256
#define N_SZ    1024
#define NROWS   (T_STEPS * B_SZ)   // 32768
#define LDSS    72                 // padded LDS stride (bf16 elems)
#define RSTR    68                 // k_rnn reduction stride (floats)
#define NGRP    16                 // row groups (16 batch rows each)
#define NCB     16                 // col blocks per group (64 cols each)

__device__ __forceinline__ float fast_tanh(float x) {
    float e = __expf(2.0f * x);
    return 1.0f - 2.0f / (e + 1.0f);   // exact at +-inf, no NaN
}

// ---------------- fp32 -> bf16 contiguous convert ----------------
__global__ void k_convert(const float* __restrict__ src, bf16* __restrict__ dst, int n) {
    int i = (blockIdx.x * blockDim.x + threadIdx.x) * 4;
    if (i < n) {
        float4 v = *(const float4*)(src + i);
        bf16x4 o;
        o.x = (bf16)v.x; o.y = (bf16)v.y; o.z = (bf16)v.z; o.w = (bf16)v.w;
        *(bf16x4*)(dst + i) = o;
    }
}

// ---------------- fp32 (R x C) -> bf16 transpose (C x R) ----------------
__global__ void k_transpose_cvt(const float* __restrict__ src, bf16* __restrict__ dst,
                                int R, int C) {
    __shared__ float tile[32][33];
    int c0 = blockIdx.x * 32;
    int r0 = blockIdx.y * 32;
    int tx = threadIdx.x & 31;
    int ty = threadIdx.x >> 5;   // 0..7
#pragma unroll
    for (int i = 0; i < 32; i += 8)
        tile[ty + i][tx] = src[(size_t)(r0 + ty + i) * C + c0 + tx];
    __syncthreads();
#pragma unroll
    for (int i = 0; i < 32; i += 8)
        dst[(size_t)(c0 + ty + i) * R + r0 + tx] = (bf16)tile[tx][ty + i];
}

// ---------------- Xproj: XH[i][n] = bf16( X[i]@Wx[:,n] + bias[n] ) ----------------
// Rows with i < B_SZ are t=0: fold in h0 = tanh(Xproj0) since h_init = 0.
__global__ __launch_bounds__(256) void k_xproj(
    const bf16* __restrict__ X, const bf16* __restrict__ Wxt,
    const float* __restrict__ bias, bf16* __restrict__ XH)
{
    __shared__ __align__(16) bf16 As[64 * LDSS];
    __shared__ __align__(16) bf16 Bs[64 * LDSS];
    const int tid  = threadIdx.x;
    const int lane = tid & 63;
    const int w    = tid >> 6;
    const int wm   = (w >> 1) * 32;
    const int wn   = (w & 1) * 32;
    const int quad = lane >> 4;
    const int l15  = lane & 15;
    const int m0 = blockIdx.x * 64;
    const int n0 = blockIdx.y * 64;

    const bf16* Ag = X + (size_t)m0 * V_SZ;
    const bf16* Bg = Wxt + (size_t)n0 * V_SZ;

    f32x4 z = {0.f, 0.f, 0.f, 0.f};
    f32x4 acc00 = z, acc01 = z, acc10 = z, acc11 = z;

    for (int k0 = 0; k0 < V_SZ; k0 += 64) {
        {
            int c = tid, row = c >> 3, col = (c & 7) * 8;
            *(bf16x8*)&As[row * LDSS + col] = *(const bf16x8*)&Ag[(size_t)row * V_SZ + k0 + col];
            *(bf16x8*)&Bs[row * LDSS + col] = *(const bf16x8*)&Bg[(size_t)row * V_SZ + k0 + col];
            c = tid + 256; row = c >> 3; col = (c & 7) * 8;
            *(bf16x8*)&As[row * LDSS + col] = *(const bf16x8*)&Ag[(size_t)row * V_SZ + k0 + col];
            *(bf16x8*)&Bs[row * LDSS + col] = *(const bf16x8*)&Bg[(size_t)row * V_SZ + k0 + col];
        }
        __syncthreads();
#pragma unroll
        for (int kc = 0; kc < 64; kc += 32) {
            bf16x8 a0 = *(const bf16x8*)&As[(wm + l15) * LDSS + kc + quad * 8];
            bf16x8 a1 = *(const bf16x8*)&As[(wm + 16 + l15) * LDSS + kc + quad * 8];
            bf16x8 b0 = *(const bf16x8*)&Bs[(wn + l15) * LDSS + kc + quad * 8];
            bf16x8 b1 = *(const bf16x8*)&Bs[(wn + 16 + l15) * LDSS + kc + quad * 8];
            acc00 = __builtin_amdgcn_mfma_f32_16x16x32_bf16(a0, b0, acc00, 0, 0, 0);
            acc01 = __builtin_amdgcn_mfma_f32_16x16x32_bf16(a0, b1, acc01, 0, 0, 0);
            acc10 = __builtin_amdgcn_mfma_f32_16x16x32_bf16(a1, b0, acc10, 0, 0, 0);
            acc11 = __builtin_amdgcn_mfma_f32_16x16x32_bf16(a1, b1, acc11, 0, 0, 0);
        }
        __syncthreads();
    }
    bf16* Out = XH + (size_t)m0 * N_SZ + n0;
    const f32x4 accs[2][2] = {{acc00, acc01}, {acc10, acc11}};
#pragma unroll
    for (int mi = 0; mi < 2; ++mi)
#pragma unroll
        for (int r = 0; r < 4; ++r) {
            int row = wm + mi * 16 + quad * 4 + r;
            bool is_t0 = (m0 + row) < B_SZ;   // t=0 rows: apply tanh (h_prev = 0)
#pragma unroll
            for (int ni = 0; ni < 2; ++ni) {
                int col = wn + ni * 16 + l15;
                float pre = accs[mi][ni][r] + bias[n0 + col];
                if (is_t0) pre = fast_tanh(pre);
                Out[(size_t)row * N_SZ + col] = (bf16)pre;
            }
        }
}

// ---------------- persistent recurrence (R6 step body + relaxed-atomic sync) -------
// 256 blocks x 512 threads, all co-resident (1 block/CU). Group g = bid>>4 owns
// batch rows [g*16,+16); col block c = bid&15 owns cols [c*64,+64). bid%8 = c%8
// -> col-sharing blocks on one XCD: B footprint 256 KB/XCD, L2-hot all steps
// (NO acquire fences / wbl2 anywhere to evict it).
// Publish: packed-uint relaxed agent atomic stores (write-through to L3) +
// raw s_waitcnt + per-group counter. Xproj read via uint agent atomic loads
// (no L2 allocation). A-loads are first-touch per t-plane => always fresh.
__global__ __launch_bounds__(512, 2) void k_rnn(
    const bf16* __restrict__ Wht,   // 1024 x 1024 = Wh^T
    bf16* __restrict__ XH,
    int* __restrict__ cnt)          // [NGRP * T_STEPS], zeroed
{
    __shared__ float red[8 * 16 * RSTR];   // 34.8 KB
    const int tid  = threadIdx.x;
    const int lane = tid & 63;
    const int w    = tid >> 6;        // 0..7
    const int quad = lane >> 4;
    const int l15  = lane & 15;
    const int g  = blockIdx.x >> 4;   // row group
    const int c  = blockIdx.x & 15;   // col block
    const int m0 = g * 16;
    const int n0 = c * 64;
    const int k0 = w * 128;

    // B fragments hoisted OUTSIDE the t-loop (64 VGPRs; budget 256)
    const bf16* Bp = Wht + (size_t)(n0 + l15) * N_SZ + k0 + quad * 8;
    bf16x8 b[4][4];
#pragma unroll
    for (int nt = 0; nt < 4; ++nt)
#pragma unroll
        for (int kc = 0; kc < 4; ++kc)
            b[nt][kc] = *(const bf16x8*)&Bp[(size_t)(nt * 16) * N_SZ + kc * 32];

    const int orow = tid >> 5;           // 0..15
    const int ocol = (tid & 31) * 2;     // 0..62
    uint* XHu = (uint*)XH;

    for (int t = 1; t < T_STEPS; ++t) {
        // Xproj prefetch (agent atomic: no L1/L2 line allocation) — in flight
        // during the poll below.
        size_t oidx = (((size_t)t * B_SZ + m0 + orow) * N_SZ + n0 + ocol) >> 1;
        uint xw = __hip_atomic_load(&XHu[oidx], __ATOMIC_RELAXED,
                                    __HIP_MEMORY_SCOPE_AGENT);

        // wait for row-group g's step t-1 to be fully published
        if (t > 1) {
            if (tid == 0) {
                while (__hip_atomic_load(&cnt[g * T_STEPS + t - 1],
                                         __ATOMIC_RELAXED, __HIP_MEMORY_SCOPE_AGENT) < NCB)
                    __builtin_amdgcn_s_sleep(2);
            }
            __syncthreads();
        }

        // A fragments (first regular-load touch of the t-1 plane => fresh L3 data)
        const bf16* Ap = XH + ((size_t)(t - 1) * B_SZ + m0 + l15) * N_SZ + k0 + quad * 8;
        bf16x8 a[4];
#pragma unroll
        for (int kc = 0; kc < 4; ++kc)
            a[kc] = *(const bf16x8*)&Ap[kc * 32];

        f32x4 z = {0.f, 0.f, 0.f, 0.f};
        f32x4 acc[4] = {z, z, z, z};
#pragma unroll
        for (int kc = 0; kc < 4; ++kc)
#pragma unroll
            for (int nt = 0; nt < 4; ++nt)
                acc[nt] = __builtin_amdgcn_mfma_f32_16x16x32_bf16(a[kc], b[nt][kc],
                                                                  acc[nt], 0, 0, 0);

        // 8-way K-reduce via LDS
#pragma unroll
        for (int nt = 0; nt < 4; ++nt)
#pragma unroll
            for (int r = 0; r < 4; ++r)
                red[(w * 16 + quad * 4 + r) * RSTR + nt * 16 + l15] = acc[nt][r];
        __syncthreads();

        float s0 = 0.f, s1 = 0.f;
#pragma unroll
        for (int w2 = 0; w2 < 8; ++w2) {
            float2 v = *(const float2*)&red[(w2 * 16 + orow) * RSTR + ocol];
            s0 += v.x; s1 += v.y;
        }
        bf16 x0 = __builtin_bit_cast(bf16, (unsigned short)(xw & 0xffff));
        bf16 x1 = __builtin_bit_cast(bf16, (unsigned short)(xw >> 16));
        bf16 r0 = (bf16)fast_tanh(s0 + (float)x0);
        bf16 r1 = (bf16)fast_tanh(s1 + (float)x1);
        uint outw = (uint)__builtin_bit_cast(unsigned short, r0)
                  | ((uint)__builtin_bit_cast(unsigned short, r1) << 16);
        // publish: write-through to L3, no dirty L2 line anywhere
        __hip_atomic_store(&XHu[oidx], outw, __ATOMIC_RELAXED,
                           __HIP_MEMORY_SCOPE_AGENT);

        // drain own stores (raw waitcnt — avoids compiler's buffer_wbl2),
        // then barrier (also protects red[] reuse), then arrive.
        asm volatile("s_waitcnt vmcnt(0)" ::: "memory");
        __syncthreads();
        if (tid == 0)
            __hip_atomic_fetch_add(&cnt[g * T_STEPS + t], 1,
                                   __ATOMIC_RELAXED, __HIP_MEMORY_SCOPE_AGENT);
    }
}

// ---------------- fused logits + log-softmax + loss ----------------
// 256 blocks x 512 threads (8 waves), 128 rows/block; wave w owns rows w*16..+16.
__global__ __launch_bounds__(512, 4) void k_loss(
    const bf16* __restrict__ XH,
    const bf16* __restrict__ Wot,    // 256 x 1024 = Wout^T
    const float* __restrict__ ob,
    const float* __restrict__ labels,
    float* __restrict__ out)
{
    __shared__ __align__(16) bf16 As[128 * LDSS];   // 18.4 KB
    __shared__ __align__(16) bf16 Bs[256 * LDSS];   // 36.9 KB
    const int tid  = threadIdx.x;
    const int lane = tid & 63;
    const int w    = tid >> 6;      // 0..7
    const int quad = lane >> 4;
    const int l15  = lane & 15;
    const int m0 = blockIdx.x * 128;

    f32x4 z = {0.f, 0.f, 0.f, 0.f};
    f32x4 acc[16];
#pragma unroll
    for (int i = 0; i < 16; ++i) acc[i] = z;

    const bf16* Ag = XH + (size_t)m0 * N_SZ;
    for (int k0 = 0; k0 < N_SZ; k0 += 64) {
#pragma unroll
        for (int c = tid; c < 1024; c += 512) {
            int row = c >> 3, col = (c & 7) * 8;
            *(bf16x8*)&As[row * LDSS + col] = *(const bf16x8*)&Ag[(size_t)row * N_SZ + k0 + col];
        }
#pragma unroll
        for (int c = tid; c < 2048; c += 512) {
            int row = c >> 3, col = (c & 7) * 8;
            *(bf16x8*)&Bs[row * LDSS + col] = *(const bf16x8*)&Wot[(size_t)row * N_SZ + k0 + col];
        }
        __syncthreads();
#pragma unroll
        for (int kc = 0; kc < 64; kc += 32) {
            bf16x8 a = *(const bf16x8*)&As[(w * 16 + l15) * LDSS + kc + quad * 8];
#pragma unroll
            for (int nt = 0; nt < 16; ++nt) {
                bf16x8 b = *(const bf16x8*)&Bs[(nt * 16 + l15) * LDSS + kc + quad * 8];
                acc[nt] = __builtin_amdgcn_mfma_f32_16x16x32_bf16(a, b, acc[nt], 0, 0, 0);
            }
        }
        __syncthreads();
    }

    float obv[16];
#pragma unroll
    for (int nt = 0; nt < 16; ++nt) obv[nt] = ob[nt * 16 + l15];

    float total = 0.f;
#pragma unroll
    for (int r = 0; r < 4; ++r) {
        int row = m0 + w * 16 + quad * 4 + r;
        float vals[16];
        float lmax = -3.0e38f;
#pragma unroll
        for (int nt = 0; nt < 16; ++nt) {
            vals[nt] = acc[nt][r] + obv[nt];
            lmax = fmaxf(lmax, vals[nt]);
        }
#pragma unroll
        for (int s = 1; s < 16; s <<= 1)
            lmax = fmaxf(lmax, __shfl_xor(lmax, s, 64));
        float sume = 0.f, labv = 0.f, labs = 0.f;
        const float* lrow = labels + (size_t)row * V_SZ;
#pragma unroll
        for (int nt = 0; nt < 16; ++nt) {
            sume += __expf(vals[nt] - lmax);
            float lb = lrow[nt * 16 + l15];
            labv += lb * vals[nt];
            labs += lb;
        }
#pragma unroll
        for (int s = 1; s < 16; s <<= 1) {
            sume += __shfl_xor(sume, s, 64);
            labv += __shfl_xor(labv, s, 64);
            labs += __shfl_xor(labs, s, 64);
        }
        float lse = lmax + __logf(sume);
        total += labs * lse - labv;
    }
    if (l15 == 0)
        atomicAdd(out, total * (1.0f / (float)NROWS));
}

extern "C" void kernel_launch(void* const* d_in, const int* in_sizes, int n_in,
                              void* d_out, int out_size, void* d_ws, size_t ws_size,
                              hipStream_t stream)
{
    const float* inputs  = (const float*)d_in[0];
    const float* labels  = (const float*)d_in[1];
    const float* weights = (const float*)d_in[2];
    const float* bias    = (const float*)d_in[3];
    const float* out_w   = (const float*)d_in[4];
    const float* out_b   = (const float*)d_in[5];
    float* out = (float*)d_out;

    char* ws = (char*)d_ws;
    bf16* XH  = (bf16*)ws;  ws += (size_t)NROWS * N_SZ * 2;   // 64 MB, Xproj then H in place
    bf16* Xb  = (bf16*)ws;  ws += (size_t)NROWS * V_SZ * 2;   // 16 MB
    bf16* Wxt = (bf16*)ws;  ws += (size_t)N_SZ * V_SZ * 2;    // 0.5 MB (Wx^T: 1024x256)
    bf16* Wht = (bf16*)ws;  ws += (size_t)N_SZ * N_SZ * 2;    // 2 MB   (Wh^T: 1024x1024)
    bf16* Wot = (bf16*)ws;  ws += (size_t)V_SZ * N_SZ * 2;    // 0.5 MB (Wo^T: 256x1024)
    int*  cnt = (int*)ws;   ws += (size_t)NGRP * T_STEPS * 4; // 8 KB sync counters

    hipMemsetAsync(out, 0, sizeof(float), stream);
    hipMemsetAsync(cnt, 0, (size_t)NGRP * T_STEPS * 4, stream);

    k_convert<<<dim3(NROWS * V_SZ / 1024), 256, 0, stream>>>(inputs, Xb, NROWS * V_SZ);
    k_transpose_cvt<<<dim3(N_SZ / 32, V_SZ / 32), 256, 0, stream>>>(weights, Wxt, V_SZ, N_SZ);
    k_transpose_cvt<<<dim3(N_SZ / 32, N_SZ / 32), 256, 0, stream>>>(
        weights + (size_t)V_SZ * N_SZ, Wht, N_SZ, N_SZ);
    k_transpose_cvt<<<dim3(V_SZ / 32, N_SZ / 32), 256, 0, stream>>>(out_w, Wot, N_SZ, V_SZ);

    k_xproj<<<dim3(NROWS / 64, N_SZ / 64), 256, 0, stream>>>(Xb, Wxt, bias, XH);

    k_rnn<<<dim3(NGRP * NCB), 512, 0, stream>>>(Wht, XH, cnt);

    k_loss<<<dim3(NROWS / 128), 512, 0, stream>>>(XH, Wot, out_b, labels, out);
}

// Round 10
// 502.154 us; speedup vs baseline: 4.0753x; 1.1173x over previous
//
#include <hip/hip_runtime.h>
#include <math.h>

typedef __bf16 bf16;
typedef __attribute__((ext_vector_type(4))) __bf16 bf16x4;
typedef __attribute__((ext_vector_type(8))) __bf16 bf16x8;
typedef __attribute__((ext_vector_type(4))) float f32x4;

#define T_STEPS 128
#define B_SZ    256
#define V_SZ    256
#define N_SZ    1024
#define NROWS   (T_STEPS * B_SZ)   // 32768
#define RSTR    68                 // step reduction stride (floats)
#define LSTR    17                 // loss reduction stride (floats)
#define NGRP    16                 // row groups (16 batch rows each)
#define NCB     16                 // col blocks per group (64 cols each)

__device__ __forceinline__ float fast_tanh(float x) {
    float e = __expf(2.0f * x);
    return 1.0f - 2.0f / (e + 1.0f);   // exact at +-inf, no NaN
}

// ---------------- fp32 -> bf16 contiguous convert ----------------
__global__ void k_convert(const float* __restrict__ src, bf16* __restrict__ dst, int n) {
    int i = (blockIdx.x * blockDim.x + threadIdx.x) * 4;
    if (i < n) {
        float4 v = *(const float4*)(src + i);
        bf16x4 o;
        o.x = (bf16)v.x; o.y = (bf16)v.y; o.z = (bf16)v.z; o.w = (bf16)v.w;
        *(bf16x4*)(dst + i) = o;
    }
}

// ---------------- fp32 (R x C) -> bf16 transpose (C x R) ----------------
__global__ void k_transpose_cvt(const float* __restrict__ src, bf16* __restrict__ dst,
                                int R, int C) {
    __shared__ float tile[32][33];
    int c0 = blockIdx.x * 32;
    int r0 = blockIdx.y * 32;
    int tx = threadIdx.x & 31;
    int ty = threadIdx.x >> 5;   // 0..7
#pragma unroll
    for (int i = 0; i < 32; i += 8)
        tile[ty + i][tx] = src[(size_t)(r0 + ty + i) * C + c0 + tx];
    __syncthreads();
#pragma unroll
    for (int i = 0; i < 32; i += 8)
        dst[(size_t)(c0 + ty + i) * R + r0 + tx] = (bf16)tile[tx][ty + i];
}

// ---------------- persistent recurrence + fused Xproj seed + fused loss GEMM -------
// 256 blocks x 512 threads (1/CU). g=bid>>4 owns batch rows [g*16,+16);
// c=bid&15 owns H cols [c*64,+64) AND vocab slice [c*16,+16) for the loss GEMM.
// Per step t: prefetch Xb A-frag -> poll group counter(t-1) -> load A=H_{t-1} ->
// acc = Xproj-seed MFMAs + Wh MFMAs -> LDS K-reduce -> +bias, tanh -> publish
// (packed-uint relaxed agent store, write-through) -> raw vmcnt drain -> arrive ->
// loss GEMM for plane t-1 reusing A (4 MFMAs) -> LDS K-reduce -> bf16 logits out.
// No acquire fences anywhere => Wht/Wxt/Wot stay L2-hot the whole kernel.
__global__ __launch_bounds__(512, 2) void k_rnn(
    const bf16* __restrict__ Xb,    // 32768 x 256 (bf16 inputs, t-major)
    const bf16* __restrict__ Wxt,   // 1024 x 256  = Wx^T
    const bf16* __restrict__ Wht,   // 1024 x 1024 = Wh^T
    const bf16* __restrict__ Wot,   // 256 x 1024  = Wo^T
    const float* __restrict__ bias,
    bf16* __restrict__ XH,          // 32768 x 1024 H states
    unsigned int* __restrict__ Lgu, // bf16-pair logits, slab layout [p][c][256][8]
    int* __restrict__ cnt)          // [NGRP * T_STEPS], zeroed
{
    __shared__ float red[8 * 16 * RSTR];   // 34.8 KB step K-reduce
    __shared__ float lred[8 * 16 * LSTR];  // 8.7 KB  loss K-reduce
    const int tid  = threadIdx.x;
    const int lane = tid & 63;
    const int w    = tid >> 6;        // 0..7
    const int quad = lane >> 4;
    const int l15  = lane & 15;
    const int g  = blockIdx.x >> 4;   // row group
    const int c  = blockIdx.x & 15;   // col block / vocab slab
    const int m0 = g * 16;
    const int n0 = c * 64;
    const int k0 = w * 128;           // K-slice for Wh / Wot GEMMs
    const int v0 = w * 32;            // K-slice for Xproj GEMM (V=256 / 8)

    // hoisted B fragments (compiler may re-load from hot L2 — fine, never invalidated)
    const bf16* Bp = Wht + (size_t)(n0 + l15) * N_SZ + k0 + quad * 8;
    bf16x8 b[4][4];
#pragma unroll
    for (int nt = 0; nt < 4; ++nt)
#pragma unroll
        for (int kc = 0; kc < 4; ++kc)
            b[nt][kc] = *(const bf16x8*)&Bp[(size_t)(nt * 16) * N_SZ + kc * 32];
    bf16x8 bx[4];
#pragma unroll
    for (int nt = 0; nt < 4; ++nt)
        bx[nt] = *(const bf16x8*)&Wxt[(size_t)(n0 + nt * 16 + l15) * V_SZ + v0 + quad * 8];
    bf16x8 bo[4];
#pragma unroll
    for (int kc = 0; kc < 4; ++kc)
        bo[kc] = *(const bf16x8*)&Wot[(size_t)(c * 16 + l15) * N_SZ + k0 + kc * 32 + quad * 8];

    const int orow = tid >> 5;           // 0..15
    const int ocol = (tid & 31) * 2;     // 0..62
    const float bias0 = bias[n0 + ocol];
    const float bias1 = bias[n0 + ocol + 1];
    unsigned int* XHu = (unsigned int*)XH;
    const f32x4 zz = {0.f, 0.f, 0.f, 0.f};

    // ---------------- t = 0: H_0 = tanh(Xproj_0 + bias) ----------------
    {
        bf16x8 ax = *(const bf16x8*)&Xb[(size_t)(m0 + l15) * V_SZ + v0 + quad * 8];
        f32x4 acc[4] = {zz, zz, zz, zz};
#pragma unroll
        for (int nt = 0; nt < 4; ++nt)
            acc[nt] = __builtin_amdgcn_mfma_f32_16x16x32_bf16(ax, bx[nt], acc[nt], 0, 0, 0);
#pragma unroll
        for (int nt = 0; nt < 4; ++nt)
#pragma unroll
            for (int r = 0; r < 4; ++r)
                red[(w * 16 + quad * 4 + r) * RSTR + nt * 16 + l15] = acc[nt][r];
        __syncthreads();
        float s0 = bias0, s1 = bias1;
#pragma unroll
        for (int w2 = 0; w2 < 8; ++w2) {
            float2 v = *(const float2*)&red[(w2 * 16 + orow) * RSTR + ocol];
            s0 += v.x; s1 += v.y;
        }
        bf16 r0 = (bf16)fast_tanh(s0);
        bf16 r1 = (bf16)fast_tanh(s1);
        unsigned int outw = (unsigned int)__builtin_bit_cast(unsigned short, r0)
                          | ((unsigned int)__builtin_bit_cast(unsigned short, r1) << 16);
        size_t oidx = (((size_t)0 * B_SZ + m0 + orow) * N_SZ + n0 + ocol) >> 1;
        __hip_atomic_store(&XHu[oidx], outw, __ATOMIC_RELAXED, __HIP_MEMORY_SCOPE_AGENT);
        asm volatile("s_waitcnt vmcnt(0)" ::: "memory");
        __syncthreads();
        if (tid == 0)
            __hip_atomic_fetch_add(&cnt[g * T_STEPS + 0], 1,
                                   __ATOMIC_RELAXED, __HIP_MEMORY_SCOPE_AGENT);
    }

    // ---------------- t = 1 .. 127 ----------------
    for (int t = 1; t < T_STEPS; ++t) {
        // Xb A-frag prefetch (read-only input, in flight through the poll)
        bf16x8 ax = *(const bf16x8*)&Xb[((size_t)t * B_SZ + m0 + l15) * V_SZ + v0 + quad * 8];

        if (tid == 0) {
            while (__hip_atomic_load(&cnt[g * T_STEPS + t - 1],
                                     __ATOMIC_RELAXED, __HIP_MEMORY_SCOPE_AGENT) < NCB)
                __builtin_amdgcn_s_sleep(2);
        }
        __syncthreads();

        // A fragments: 16 rows of H_{t-1} (first regular-load touch => fresh from L3)
        const bf16* Ap = XH + ((size_t)(t - 1) * B_SZ + m0 + l15) * N_SZ + k0 + quad * 8;
        bf16x8 a[4];
#pragma unroll
        for (int kc = 0; kc < 4; ++kc)
            a[kc] = *(const bf16x8*)&Ap[kc * 32];

        // acc = Xproj seed + A @ Wh^T-slice
        f32x4 acc[4] = {zz, zz, zz, zz};
#pragma unroll
        for (int nt = 0; nt < 4; ++nt)
            acc[nt] = __builtin_amdgcn_mfma_f32_16x16x32_bf16(ax, bx[nt], acc[nt], 0, 0, 0);
#pragma unroll
        for (int kc = 0; kc < 4; ++kc)
#pragma unroll
            for (int nt = 0; nt < 4; ++nt)
                acc[nt] = __builtin_amdgcn_mfma_f32_16x16x32_bf16(a[kc], b[nt][kc],
                                                                  acc[nt], 0, 0, 0);

        // 8-way K-reduce
#pragma unroll
        for (int nt = 0; nt < 4; ++nt)
#pragma unroll
            for (int r = 0; r < 4; ++r)
                red[(w * 16 + quad * 4 + r) * RSTR + nt * 16 + l15] = acc[nt][r];
        __syncthreads();

        float s0 = bias0, s1 = bias1;
#pragma unroll
        for (int w2 = 0; w2 < 8; ++w2) {
            float2 v = *(const float2*)&red[(w2 * 16 + orow) * RSTR + ocol];
            s0 += v.x; s1 += v.y;
        }
        bf16 r0 = (bf16)fast_tanh(s0);
        bf16 r1 = (bf16)fast_tanh(s1);
        unsigned int outw = (unsigned int)__builtin_bit_cast(unsigned short, r0)
                          | ((unsigned int)__builtin_bit_cast(unsigned short, r1) << 16);
        size_t oidx = (((size_t)t * B_SZ + m0 + orow) * N_SZ + n0 + ocol) >> 1;
        __hip_atomic_store(&XHu[oidx], outw, __ATOMIC_RELAXED, __HIP_MEMORY_SCOPE_AGENT);
        asm volatile("s_waitcnt vmcnt(0)" ::: "memory");
        __syncthreads();
        if (tid == 0)
            __hip_atomic_fetch_add(&cnt[g * T_STEPS + t], 1,
                                   __ATOMIC_RELAXED, __HIP_MEMORY_SCOPE_AGENT);

        // ---- loss GEMM for plane t-1, reusing a[] (off the inter-block chain) ----
        f32x4 lacc = zz;
#pragma unroll
        for (int kc = 0; kc < 4; ++kc)
            lacc = __builtin_amdgcn_mfma_f32_16x16x32_bf16(a[kc], bo[kc], lacc, 0, 0, 0);
#pragma unroll
        for (int r = 0; r < 4; ++r)
            lred[(w * 16 + quad * 4 + r) * LSTR + l15] = lacc[r];
        __syncthreads();
        if (tid < 128) {
            int row = tid >> 3, vp = tid & 7;
            float sa = 0.f, sb = 0.f;
#pragma unroll
            for (int w2 = 0; w2 < 8; ++w2) {
                sa += lred[(w2 * 16 + row) * LSTR + vp * 2];
                sb += lred[(w2 * 16 + row) * LSTR + vp * 2 + 1];
            }
            bf16 pa = (bf16)sa, pb = (bf16)sb;
            unsigned int pw = (unsigned int)__builtin_bit_cast(unsigned short, pa)
                            | ((unsigned int)__builtin_bit_cast(unsigned short, pb) << 16);
            Lgu[(((size_t)(t - 1) * 16 + c) * B_SZ + m0 + row) * 8 + vp] = pw;
        }
        __syncthreads();   // protect lred before next iteration
    }

    // ---------------- tail: loss GEMM for plane 127 ----------------
    if (tid == 0) {
        while (__hip_atomic_load(&cnt[g * T_STEPS + T_STEPS - 1],
                                 __ATOMIC_RELAXED, __HIP_MEMORY_SCOPE_AGENT) < NCB)
            __builtin_amdgcn_s_sleep(2);
    }
    __syncthreads();
    {
        const bf16* Ap = XH + ((size_t)(T_STEPS - 1) * B_SZ + m0 + l15) * N_SZ + k0 + quad * 8;
        bf16x8 a[4];
#pragma unroll
        for (int kc = 0; kc < 4; ++kc)
            a[kc] = *(const bf16x8*)&Ap[kc * 32];
        f32x4 lacc = zz;
#pragma unroll
        for (int kc = 0; kc < 4; ++kc)
            lacc = __builtin_amdgcn_mfma_f32_16x16x32_bf16(a[kc], bo[kc], lacc, 0, 0, 0);
#pragma unroll
        for (int r = 0; r < 4; ++r)
            lred[(w * 16 + quad * 4 + r) * LSTR + l15] = lacc[r];
        __syncthreads();
        if (tid < 128) {
            int row = tid >> 3, vp = tid & 7;
            float sa = 0.f, sb = 0.f;
#pragma unroll
            for (int w2 = 0; w2 < 8; ++w2) {
                sa += lred[(w2 * 16 + row) * LSTR + vp * 2];
                sb += lred[(w2 * 16 + row) * LSTR + vp * 2 + 1];
            }
            bf16 pa = (bf16)sa, pb = (bf16)sb;
            unsigned int pw = (unsigned int)__builtin_bit_cast(unsigned short, pa)
                            | ((unsigned int)__builtin_bit_cast(unsigned short, pb) << 16);
            Lgu[(((size_t)(T_STEPS - 1) * 16 + c) * B_SZ + m0 + row) * 8 + vp] = pw;
        }
    }
}

// ---------------- final: log-softmax + weighted-label loss over bf16 logits --------
// 256 blocks x 256 threads (4 waves); block handles 128 rows, wave 32 rows.
// Logits layout: [plane][cslab 16][row-in-plane 256][16 vocab] bf16.
__global__ __launch_bounds__(256) void k_lred(
    const bf16* __restrict__ Lg,
    const float* __restrict__ labels,
    const float* __restrict__ ob,
    float* __restrict__ out)
{
    __shared__ float bt[4];
    const int tid  = threadIdx.x;
    const int lane = tid & 63;
    const int w    = tid >> 6;       // 0..3
    const int cs   = lane >> 2;      // vocab slab 0..15
    const int vi   = (lane & 3) * 4; // offset in slab
    const float4 ob4 = *(const float4*)&ob[cs * 16 + vi];

    float wtot = 0.f;
    for (int i = 0; i < 32; ++i) {
        int row  = blockIdx.x * 128 + w * 32 + i;
        int p    = row >> 8;
        int brow = row & 255;
        bf16x4 lv = *(const bf16x4*)&Lg[(((size_t)p * 16 + cs) * B_SZ + brow) * 16 + vi];
        float l0 = (float)lv.x + ob4.x;
        float l1 = (float)lv.y + ob4.y;
        float l2 = (float)lv.z + ob4.z;
        float l3 = (float)lv.w + ob4.w;
        float mx = fmaxf(fmaxf(l0, l1), fmaxf(l2, l3));
#pragma unroll
        for (int s = 1; s < 64; s <<= 1)
            mx = fmaxf(mx, __shfl_xor(mx, s, 64));
        float sume = __expf(l0 - mx) + __expf(l1 - mx) + __expf(l2 - mx) + __expf(l3 - mx);
        const float4 lb = *(const float4*)&labels[(size_t)row * V_SZ + cs * 16 + vi];
        float labs = lb.x + lb.y + lb.z + lb.w;
        float labv = lb.x * l0 + lb.y * l1 + lb.z * l2 + lb.w * l3;
#pragma unroll
        for (int s = 1; s < 64; s <<= 1) {
            sume += __shfl_xor(sume, s, 64);
            labs += __shfl_xor(labs, s, 64);
            labv += __shfl_xor(labv, s, 64);
        }
        float lse = mx + __logf(sume);
        wtot += labs * lse - labv;
    }
    if (lane == 0) bt[w] = wtot;
    __syncthreads();
    if (tid == 0)
        atomicAdd(out, (bt[0] + bt[1] + bt[2] + bt[3]) * (1.0f / (float)NROWS));
}

extern "C" void kernel_launch(void* const* d_in, const int* in_sizes, int n_in,
                              void* d_out, int out_size, void* d_ws, size_t ws_size,
                              hipStream_t stream)
{
    const float* inputs  = (const float*)d_in[0];
    const float* labels  = (const float*)d_in[1];
    const float* weights = (const float*)d_in[2];
    const float* bias    = (const float*)d_in[3];
    const float* out_w   = (const float*)d_in[4];
    const float* out_b   = (const float*)d_in[5];
    float* out = (float*)d_out;

    char* ws = (char*)d_ws;
    bf16* XH  = (bf16*)ws;  ws += (size_t)NROWS * N_SZ * 2;   // 64 MB H states
    bf16* Xb  = (bf16*)ws;  ws += (size_t)NROWS * V_SZ * 2;   // 16 MB
    bf16* Lg  = (bf16*)ws;  ws += (size_t)NROWS * V_SZ * 2;   // 16 MB bf16 logits
    bf16* Wxt = (bf16*)ws;  ws += (size_t)N_SZ * V_SZ * 2;    // 0.5 MB (Wx^T)
    bf16* Wht = (bf16*)ws;  ws += (size_t)N_SZ * N_SZ * 2;    // 2 MB   (Wh^T)
    bf16* Wot = (bf16*)ws;  ws += (size_t)V_SZ * N_SZ * 2;    // 0.5 MB (Wo^T)
    int*  cnt = (int*)ws;   ws += (size_t)NGRP * T_STEPS * 4; // 8 KB sync counters

    hipMemsetAsync(out, 0, sizeof(float), stream);
    hipMemsetAsync(cnt, 0, (size_t)NGRP * T_STEPS * 4, stream);

    k_convert<<<dim3(NROWS * V_SZ / 1024), 256, 0, stream>>>(inputs, Xb, NROWS * V_SZ);
    k_transpose_cvt<<<dim3(N_SZ / 32, V_SZ / 32), 256, 0, stream>>>(weights, Wxt, V_SZ, N_SZ);
    k_transpose_cvt<<<dim3(N_SZ / 32, N_SZ / 32), 256, 0, stream>>>(
        weights + (size_t)V_SZ * N_SZ, Wht, N_SZ, N_SZ);
    k_transpose_cvt<<<dim3(V_SZ / 32, N_SZ / 32), 256, 0, stream>>>(out_w, Wot, N_SZ, V_SZ);

    k_rnn<<<dim3(NGRP * NCB), 512, 0, stream>>>(Xb, Wxt, Wht, Wot, bias, XH,
                                                (unsigned int*)Lg, cnt);

    k_lred<<<dim3(NROWS / 128), 256, 0, stream>>>(Lg, labels, out_b, out);
}